// Round 11
// baseline (246.219 us; speedup 1.0000x reference)
//
#include <hip/hip_runtime.h>
#include <hip/hip_bf16.h>
#include <math.h>

#define B_ 2
#define T_ 2048
#define D_ 1024
#define H_ 16
#define HD 64

typedef __bf16 bf16;
typedef bf16 bf16x8 __attribute__((ext_vector_type(8)));
typedef bf16 bf16x4 __attribute__((ext_vector_type(4)));
typedef short short4v __attribute__((ext_vector_type(4)));
typedef float f32x4 __attribute__((ext_vector_type(4)));

// async global->LDS, 16B per lane. LDS dest must be wave-uniform base + lane*16 (m104/m108).
#define GL2LDS16(g, l) __builtin_amdgcn_global_load_lds(                      \
    (const __attribute__((address_space(1))) void*)(g),                       \
    (__attribute__((address_space(3))) void*)(l), 16, 0, 0)

// 16x16x16 bf16 MFMA (K=16): gfx90a-era builtin name; guarded from the host pass.
static __device__ __forceinline__ f32x4 mfma16x16x16(bf16x4 a, bf16x4 b, f32x4 c) {
#if defined(__HIP_DEVICE_COMPILE__)
# if __has_builtin(__builtin_amdgcn_mfma_f32_16x16x16bf16_1k)
    return __builtin_amdgcn_mfma_f32_16x16x16bf16_1k(
        __builtin_bit_cast(short4v, a), __builtin_bit_cast(short4v, b), c, 0, 0, 0);
# else
    asm("v_mfma_f32_16x16x16_bf16 %0, %1, %2, %0" : "+v"(c) : "v"(a), "v"(b));
    return c;
# endif
#else
    (void)a; (void)b;
    return c;
#endif
}

// ------------------- fused prep: z 0..3 = transpose W_z -> bf16 [n][k]; z 4..19 = cast x
__global__ __launch_bounds__(256) void prep_inputs(const float* __restrict__ x,
                                                   const float* __restrict__ W0,
                                                   const float* __restrict__ W1,
                                                   const float* __restrict__ W2,
                                                   const float* __restrict__ W3,
                                                   bf16* __restrict__ xb,
                                                   bf16* __restrict__ Wt) {
    const int z = blockIdx.z;
    const int tid = threadIdx.x;
    if (z >= 4) {
        size_t i = ((((size_t)(z - 4) * 256 + blockIdx.y * 16 + blockIdx.x) * 256) + tid) * 4;
        float4 v = *(const float4*)(x + i);
        bf16 tmp[4] = {(bf16)v.x, (bf16)v.y, (bf16)v.z, (bf16)v.w};
        *(uint2*)(xb + i) = *(const uint2*)tmp;
        return;
    }
    __shared__ bf16 tile[64 * 72];
    const float* W = (z == 0) ? W0 : (z == 1) ? W1 : (z == 2) ? W2 : W3;
    bf16* out = Wt + (size_t)z * D_ * D_;
    const int k0 = blockIdx.y * 64, n0 = blockIdx.x * 64;
    for (int it = 0; it < 4; ++it) {
        int idx = it * 256 + tid;
        int r = idx >> 4;                // k row
        int c4 = (idx & 15) << 2;        // n col
        float4 v = *(const float4*)(W + (size_t)(k0 + r) * D_ + n0 + c4);
        tile[(c4 + 0) * 72 + r] = (bf16)v.x;
        tile[(c4 + 1) * 72 + r] = (bf16)v.y;
        tile[(c4 + 2) * 72 + r] = (bf16)v.z;
        tile[(c4 + 3) * 72 + r] = (bf16)v.w;
    }
    __syncthreads();
    for (int it = 0; it < 2; ++it) {
        int idx = it * 256 + tid;
        int r = idx >> 3;                // n row
        int c8 = (idx & 7) << 3;         // k col
        bf16x8 v = *(const bf16x8*)&tile[r * 72 + c8];
        *(bf16x8*)(out + (size_t)(n0 + r) * D_ + k0 + c8) = v;
    }
}

// ---------------------------------------------------------------- MFMA GEMM (BM=128, BN=64, BK=64)
// Round-9 version (single-buffered; R10's explicit dbuf was neutral -> reverted).
// Q-slice epilogue folds the attention scale 0.125*log2e into Q (free mul here).
// mode 0: z=0(Q),1(K) -> [B,H,T,hd] (swapped: r->d); z=2(V) -> [B,H,hd,T] (unswapped: r->t)
// mode 1: out fp32 row-major (swapped: r->n, 16B store)
__global__ __launch_bounds__(256) void gemm_bf16(const bf16* __restrict__ A,
                                                 const bf16* __restrict__ Bt,
                                                 void* __restrict__ Cout,
                                                 int M, int N, int K, int mode) {
    __shared__ bf16 As[2][128 * 32];
    __shared__ bf16 Bs[2][64 * 32];
    const int tid = threadIdx.x;
    const int wave = tid >> 6, lane = tid & 63;
    const int quad = lane >> 4, l16 = lane & 15;
    const int wr = wave >> 1, wc = wave & 1;
    const int m0 = blockIdx.y * 128, n0 = blockIdx.x * 64;
    const int z = blockIdx.z;
    const bf16* Bz = Bt + (size_t)z * N * K;
    const bool swapped = (mode == 1) || (z < 2);

    const int lrow = lane >> 2, lcol = (lane & 3) << 3;
    const bf16* ag = A  + (size_t)(m0 + wave * 32 + lrow) * K + lcol;
    const bf16* bg = Bz + (size_t)(n0 + wave * 16 + lrow) * K + lcol;
    const int a_off = (wave * 32 + lrow) * 32 + lcol;
    const int b_off = (wave * 16 + lrow) * 32 + lcol;

    f32x4 acc[4][2];
    for (int mi = 0; mi < 4; ++mi)
        for (int ni = 0; ni < 2; ++ni) acc[mi][ni] = (f32x4){0.f, 0.f, 0.f, 0.f};

    for (int kb = 0; kb < K; kb += 64) {
        GL2LDS16(ag + kb,                       &As[0][a_off]);
        GL2LDS16(ag + (size_t)16 * K + kb,      &As[0][a_off + 16 * 32]);
        GL2LDS16(ag + kb + 32,                  &As[1][a_off]);
        GL2LDS16(ag + (size_t)16 * K + kb + 32, &As[1][a_off + 16 * 32]);
        GL2LDS16(bg + kb,                       &Bs[0][b_off]);
        GL2LDS16(bg + kb + 32,                  &Bs[1][b_off]);
        __syncthreads();   // drains vmcnt -> LDS writes visible

        for (int half = 0; half < 2; ++half) {
            bf16x8 af[4], bfr[2];
            for (int mi = 0; mi < 4; ++mi)
                af[mi] = *(const bf16x8*)&As[half][(wr * 64 + mi * 16 + l16) * 32 + quad * 8];
            for (int ni = 0; ni < 2; ++ni)
                bfr[ni] = *(const bf16x8*)&Bs[half][(wc * 32 + ni * 16 + l16) * 32 + quad * 8];
            if (swapped) {
                for (int mi = 0; mi < 4; ++mi)
                    for (int ni = 0; ni < 2; ++ni)
                        acc[mi][ni] = __builtin_amdgcn_mfma_f32_16x16x32_bf16(
                            bfr[ni], af[mi], acc[mi][ni], 0, 0, 0);
            } else {
                for (int mi = 0; mi < 4; ++mi)
                    for (int ni = 0; ni < 2; ++ni)
                        acc[mi][ni] = __builtin_amdgcn_mfma_f32_16x16x32_bf16(
                            af[mi], bfr[ni], acc[mi][ni], 0, 0, 0);
            }
        }
        __syncthreads();
    }

    if (mode == 0) {
        bf16* Cb = (bf16*)Cout + (size_t)z * M * N;
        const float qscale = (z == 0) ? 0.180336887f : 1.0f;  // 0.125 * log2(e) folded into Q
        if (z < 2) {
            for (int mi = 0; mi < 4; ++mi)
                for (int ni = 0; ni < 2; ++ni) {
                    int m = m0 + wr * 64 + mi * 16 + l16;
                    int n = n0 + wc * 32 + ni * 16 + quad * 4;
                    int b = m >> 11, t = m & (T_ - 1);
                    int h = n >> 6, d = n & (HD - 1);
                    bf16 o4[4];
                    for (int r = 0; r < 4; ++r) o4[r] = (bf16)(acc[mi][ni][r] * qscale);
                    *(uint2*)&Cb[(((((size_t)b * H_ + h) * T_ + t) << 6) + d)] =
                        *(const uint2*)o4;
                }
        } else {
            for (int mi = 0; mi < 4; ++mi)
                for (int ni = 0; ni < 2; ++ni) {
                    int m = m0 + wr * 64 + mi * 16 + quad * 4;
                    int n = n0 + wc * 32 + ni * 16 + l16;
                    int b = m >> 11, t = m & (T_ - 1);
                    int h = n >> 6, d = n & (HD - 1);
                    bf16 o4[4];
                    for (int r = 0; r < 4; ++r) o4[r] = (bf16)acc[mi][ni][r];
                    *(uint2*)&Cb[((((size_t)b * H_ + h) * HD + d) * T_ + t)] =
                        *(const uint2*)o4;
                }
        }
    } else {
        float* Cf = (float*)Cout;
        for (int mi = 0; mi < 4; ++mi)
            for (int ni = 0; ni < 2; ++ni) {
                int m = m0 + wr * 64 + mi * 16 + l16;
                int n = n0 + wc * 32 + ni * 16 + quad * 4;
                *(f32x4*)&Cf[(size_t)m * N + n] = acc[mi][ni];
            }
    }
}

// ---------------------------------------------------------------- flash attention
// Br=128 (8 waves, 512 thr), Bc=128, S^T form. Q pre-scaled by 0.125*log2e in GEMM.
// Items per bh (LPT, descending size): qt>=8 chunk0 = tiles [0,8) (mask-free),
// chunk1 = tiles [8, qt+1); qt<8 full. 24 items; staged tile feeds 128 q-rows.
__device__ __constant__ unsigned char ITEM_QT[24] = {
    8,9,10,11,12,13,14,15, 7,15, 6,14, 5,13, 4,12, 3,11, 2,10, 1,9, 0,8};
__device__ __constant__ unsigned char ITEM_KIND[24] = {  // 0=full 1=chunk0 2=chunk1
    1,1,1,1,1,1,1,1, 0,2, 0,2, 0,2, 0,2, 0,2, 0,2, 0,2, 0,2};

#define LDK 72
#define LDP 136

__global__ __launch_bounds__(512, 8) void attn_kernel(const bf16* __restrict__ Q,
                                                      const bf16* __restrict__ K,
                                                      const bf16* __restrict__ Vt,
                                                      bf16* __restrict__ O,
                                                      float* __restrict__ Opart,
                                                      float2* __restrict__ ML) {
    __shared__ bf16 Ks[128 * LDK];  // [key][dim]
    __shared__ bf16 Vs[64 * LDP];   // [dim][key]

    const int bh = blockIdx.x;                 // 0..31
    const int item = blockIdx.y;               // 0..23 (descending size)
    const int qt = ITEM_QT[item];              // 128-row q tile
    const int kind = ITEM_KIND[item];
    const int h = bh & (H_ - 1), b = bh >> 4;
    const int tid = threadIdx.x;
    const int wave = tid >> 6, lane = tid & 63;
    const int quad = lane >> 4, l16 = lane & 15;

    const bf16* Qb = Q + (size_t)bh * T_ * HD;
    const bf16* Kb = K + (size_t)bh * T_ * HD;
    const bf16* Vb = Vt + (size_t)bh * HD * T_;   // [hd][T]

    const float slope2 = exp2f(-0.5f * (float)(h + 1)) * 1.44269504f;  // log2-domain slope

    bf16x8 qf[2];
    {
        const bf16* qrow = Qb + (size_t)(qt * 128 + wave * 16 + l16) * HD + quad * 8;
        qf[0] = *(const bf16x8*)(qrow);
        qf[1] = *(const bf16x8*)(qrow + 32);
    }

    f32x4 acc[4];                    // O^T: d = df*16+quad*4+r, query = l16
    for (int df = 0; df < 4; ++df) acc[df] = (f32x4){0.f, 0.f, 0.f, 0.f};
    float m_run = -INFINITY, l_run = 0.f;

    const int qglob = qt * 128 + wave * 16 + l16;
    const int nkt = qt + 1;                        // 128-key tiles for full row
    const int kt0 = (kind == 2) ? 8 : 0;
    const int kt1 = (kind == 1) ? 8 : nkt;

    for (int kt = kt0; kt < kt1; ++kt) {
        const bool last = (kt == nkt - 1);         // chunk0 never reaches nkt-1
        __syncthreads();
        for (int it = 0; it < 2; ++it) {
            int idx = it * 512 + tid;              // 1024 slots
            int rk = idx >> 3, ck = (idx & 7) << 3;
            *(bf16x8*)&Ks[rk * LDK + ck] =
                *(const bf16x8*)(Kb + (size_t)(kt * 128 + rk) * HD + ck);
            int rv = idx >> 4, cv = (idx & 15) << 3;
            *(bf16x8*)&Vs[rv * LDP + cv] =
                *(const bf16x8*)(Vb + (size_t)rv * T_ + kt * 128 + cv);
        }
        __syncthreads();

        f32x4 s[8];
        for (int nf = 0; nf < 8; ++nf) {
            bf16x8 kf0 = *(const bf16x8*)&Ks[(nf * 16 + l16) * LDK + quad * 8];
            bf16x8 kf1 = *(const bf16x8*)&Ks[(nf * 16 + l16) * LDK + 32 + quad * 8];
            f32x4 zz = (f32x4){0.f, 0.f, 0.f, 0.f};
            zz = __builtin_amdgcn_mfma_f32_16x16x32_bf16(kf0, qf[0], zz, 0, 0, 0);
            zz = __builtin_amdgcn_mfma_f32_16x16x32_bf16(kf1, qf[1], zz, 0, 0, 0);
            s[nf] = zz;
        }

        // Q pre-scaled -> s is already in log2 domain; add alibi, mask last tile
        const int jbase = kt * 128 + quad * 4;
        for (int nf = 0; nf < 8; ++nf)
            for (int r = 0; r < 4; ++r) {
                int j = jbase + nf * 16 + r;
                s[nf][r] = s[nf][r] + slope2 * (float)(j - (T_ - 1));
            }
        if (last) {
            for (int nf = 0; nf < 8; ++nf)
                for (int r = 0; r < 4; ++r)
                    if (jbase + nf * 16 + r > qglob) s[nf][r] = -INFINITY;
        }

        float mx = -INFINITY;
        for (int nf = 0; nf < 8; ++nf) {
            float a = fmaxf(fmaxf(s[nf][0], s[nf][1]), fmaxf(s[nf][2], s[nf][3]));
            mx = fmaxf(mx, a);
        }
        mx = fmaxf(mx, __shfl_xor(mx, 16, 64));
        mx = fmaxf(mx, __shfl_xor(mx, 32, 64));
        const float mnew = fmaxf(m_run, mx);
        const float alpha = exp2f(m_run - mnew);
        m_run = mnew;

        float rs = 0.f;
        bf16x4 pf[8];
        for (int nf = 0; nf < 8; ++nf) {
            float p0 = exp2f(s[nf][0] - mnew);
            float p1 = exp2f(s[nf][1] - mnew);
            float p2 = exp2f(s[nf][2] - mnew);
            float p3 = exp2f(s[nf][3] - mnew);
            rs += (p0 + p1) + (p2 + p3);
            pf[nf] = (bf16x4){(bf16)p0, (bf16)p1, (bf16)p2, (bf16)p3};
        }
        rs += __shfl_xor(rs, 16, 64);
        rs += __shfl_xor(rs, 32, 64);
        l_run = l_run * alpha + rs;
        for (int df = 0; df < 4; ++df) acc[df] *= alpha;

        for (int nf = 0; nf < 8; ++nf)
            for (int df = 0; df < 4; ++df) {
                bf16x4 vf = *(const bf16x4*)&Vs[(df * 16 + l16) * LDP + nf * 16 + quad * 4];
                acc[df] = mfma16x16x16(vf, pf[nf], acc[df]);
            }
    }

    if (kind == 0) {
        const float inv = 1.0f / l_run;
        for (int df = 0; df < 4; ++df) {
            bf16 o4[4];
            for (int r = 0; r < 4; ++r) o4[r] = (bf16)(acc[df][r] * inv);
            *(uint2*)&O[(((size_t)b * T_ + qglob) * H_ + h) * HD + df * 16 + quad * 4] =
                *(const uint2*)o4;
        }
    } else {
        const int pidx = (bh * 8 + (qt - 8)) * 2 + (kind == 2 ? 1 : 0);
        const int ql = wave * 16 + l16;        // 0..127
        float* dst = Opart + (size_t)pidx * 8192 + ql * 64;
        for (int df = 0; df < 4; ++df)
            *(f32x4*)&dst[df * 16 + quad * 4] = acc[df];
        if (quad == 0) ML[pidx * 128 + ql] = make_float2(m_run, l_run);
    }
}

// ---------------------------------------------------------------- partial merge
// grid (8, 32) x 512 thr: q = tid>>2 (0..127), d-chunk = (tid&3)*16.
__global__ __launch_bounds__(512) void attn_merge(const float* __restrict__ Opart,
                                                  const float2* __restrict__ ML,
                                                  bf16* __restrict__ O) {
    const int qt = 8 + blockIdx.x, bh = blockIdx.y;
    const int h = bh & (H_ - 1), b = bh >> 4;
    const int tid = threadIdx.x;
    const int q = tid >> 2, dc = (tid & 3) << 4;
    const int p0 = (bh * 8 + blockIdx.x) * 2, p1 = p0 + 1;

    const float2 ml0 = ML[p0 * 128 + q], ml1 = ML[p1 * 128 + q];
    const float M = fmaxf(ml0.x, ml1.x);
    const float e0 = exp2f(ml0.x - M), e1 = exp2f(ml1.x - M);
    const float inv = 1.0f / (e0 * ml0.y + e1 * ml1.y);

    const float* a = Opart + (size_t)p0 * 8192 + q * 64 + dc;
    const float* c = Opart + (size_t)p1 * 8192 + q * 64 + dc;
    bf16 o16[16];
    for (int j = 0; j < 4; ++j) {
        f32x4 va = *(const f32x4*)(a + j * 4);
        f32x4 vc = *(const f32x4*)(c + j * 4);
        for (int r = 0; r < 4; ++r)
            o16[j * 4 + r] = (bf16)((va[r] * e0 + vc[r] * e1) * inv);
    }
    const int t = qt * 128 + q;
    bf16* dst = O + (((size_t)b * T_ + t) * H_ + h) * HD + dc;
    *(bf16x8*)dst = *(const bf16x8*)o16;
    *(bf16x8*)(dst + 8) = *(const bf16x8*)(o16 + 8);
}

// ---------------------------------------------------------------- launch
extern "C" void kernel_launch(void* const* d_in, const int* in_sizes, int n_in,
                              void* d_out, int out_size, void* d_ws, size_t ws_size,
                              hipStream_t stream) {
    const float* x  = (const float*)d_in[0];
    const float* Wq = (const float*)d_in[1];
    const float* Wk = (const float*)d_in[2];
    const float* Wv = (const float*)d_in[3];
    const float* Wo = (const float*)d_in[4];
    float* out = (float*)d_out;

    const size_t M = (size_t)B_ * T_;        // 4096
    const size_t XE = M * D_;                // 4 Mi elems
    const size_t WE = (size_t)D_ * D_;       // 1 Mi elems

    char* ws = (char*)d_ws;
    size_t off = 0;
    auto carve = [&](size_t bytes) {
        void* p = ws + off;
        off += (bytes + 255) & ~(size_t)255;
        return p;
    };
    bf16* xb  = (bf16*)carve(XE * 2);        // x bf16; reused as attn_out later
    bf16* Wt  = (bf16*)carve(4 * WE * 2);    // Wq,Wk,Wv,Wo transposed [N][K]
    bf16* QKV = (bf16*)carve(3 * XE * 2);    // Q,K [B,H,T,hd]; V [B,H,hd,T]
    float*  Opart = (float*)carve(32 * 8 * 2 * 8192 * sizeof(float));    // 16.8 MB
    float2* MLbuf = (float2*)carve(32 * 8 * 2 * 128 * sizeof(float2));   // 0.5 MB
    bf16* attn = xb;  // safe: xb fully consumed by QKV gemm before attn_kernel runs

    prep_inputs<<<dim3(16, 16, 20), 256, 0, stream>>>(x, Wq, Wk, Wv, Wo, xb, Wt);

    gemm_bf16<<<dim3(D_ / 64, M / 128, 3), 256, 0, stream>>>(xb, Wt, QKV,
                                                             (int)M, D_, D_, 0);
    attn_kernel<<<dim3(32, 24), 512, 0, stream>>>(QKV, QKV + XE, QKV + 2 * XE,
                                                  attn, Opart, MLbuf);
    attn_merge<<<dim3(8, 32), 512, 0, stream>>>(Opart, MLbuf, attn);
    gemm_bf16<<<dim3(D_ / 64, M / 128, 1), 256, 0, stream>>>(attn, Wt + 3 * WE, out,
                                                             (int)M, D_, D_, 1);
}

// Round 12
// 204.640 us; speedup vs baseline: 1.2032x; 1.2032x over previous
//
#include <hip/hip_runtime.h>
#include <hip/hip_bf16.h>
#include <math.h>

#define B_ 2
#define T_ 2048
#define D_ 1024
#define H_ 16
#define HD 64

typedef __bf16 bf16;
typedef bf16 bf16x8 __attribute__((ext_vector_type(8)));
typedef bf16 bf16x4 __attribute__((ext_vector_type(4)));
typedef short short4v __attribute__((ext_vector_type(4)));
typedef float f32x4 __attribute__((ext_vector_type(4)));

// async global->LDS, 16B per lane. LDS dest must be wave-uniform base + lane*16 (m104/m108).
#define GL2LDS16(g, l) __builtin_amdgcn_global_load_lds(                      \
    (const __attribute__((address_space(1))) void*)(g),                       \
    (__attribute__((address_space(3))) void*)(l), 16, 0, 0)

// 16x16x16 bf16 MFMA (K=16): gfx90a-era builtin name; guarded from the host pass.
static __device__ __forceinline__ f32x4 mfma16x16x16(bf16x4 a, bf16x4 b, f32x4 c) {
#if defined(__HIP_DEVICE_COMPILE__)
# if __has_builtin(__builtin_amdgcn_mfma_f32_16x16x16bf16_1k)
    return __builtin_amdgcn_mfma_f32_16x16x16bf16_1k(
        __builtin_bit_cast(short4v, a), __builtin_bit_cast(short4v, b), c, 0, 0, 0);
# else
    asm("v_mfma_f32_16x16x16_bf16 %0, %1, %2, %0" : "+v"(c) : "v"(a), "v"(b));
    return c;
# endif
#else
    (void)a; (void)b;
    return c;
#endif
}

// ------------------- fused prep: z 0..3 = transpose W_z -> bf16 [n][k]; z 4..19 = cast x
__global__ __launch_bounds__(256) void prep_inputs(const float* __restrict__ x,
                                                   const float* __restrict__ W0,
                                                   const float* __restrict__ W1,
                                                   const float* __restrict__ W2,
                                                   const float* __restrict__ W3,
                                                   bf16* __restrict__ xb,
                                                   bf16* __restrict__ Wt) {
    const int z = blockIdx.z;
    const int tid = threadIdx.x;
    if (z >= 4) {
        size_t i = ((((size_t)(z - 4) * 256 + blockIdx.y * 16 + blockIdx.x) * 256) + tid) * 4;
        float4 v = *(const float4*)(x + i);
        bf16 tmp[4] = {(bf16)v.x, (bf16)v.y, (bf16)v.z, (bf16)v.w};
        *(uint2*)(xb + i) = *(const uint2*)tmp;
        return;
    }
    __shared__ bf16 tile[64 * 72];
    const float* W = (z == 0) ? W0 : (z == 1) ? W1 : (z == 2) ? W2 : W3;
    bf16* out = Wt + (size_t)z * D_ * D_;
    const int k0 = blockIdx.y * 64, n0 = blockIdx.x * 64;
    for (int it = 0; it < 4; ++it) {
        int idx = it * 256 + tid;
        int r = idx >> 4;                // k row
        int c4 = (idx & 15) << 2;        // n col
        float4 v = *(const float4*)(W + (size_t)(k0 + r) * D_ + n0 + c4);
        tile[(c4 + 0) * 72 + r] = (bf16)v.x;
        tile[(c4 + 1) * 72 + r] = (bf16)v.y;
        tile[(c4 + 2) * 72 + r] = (bf16)v.z;
        tile[(c4 + 3) * 72 + r] = (bf16)v.w;
    }
    __syncthreads();
    for (int it = 0; it < 2; ++it) {
        int idx = it * 256 + tid;
        int r = idx >> 3;                // n row
        int c8 = (idx & 7) << 3;         // k col
        bf16x8 v = *(const bf16x8*)&tile[r * 72 + c8];
        *(bf16x8*)(out + (size_t)(n0 + r) * D_ + k0 + c8) = v;
    }
}

// ---------------------------------------------------------------- MFMA GEMM (BM=128, BN=64, BK=64)
// Round-9 version. Q-slice epilogue folds the attention scale 0.125*log2e into Q.
// mode 0: z=0(Q),1(K) -> [B,H,T,hd] (swapped: r->d); z=2(V) -> [B,H,hd,T] (unswapped: r->t)
// mode 1: out fp32 row-major (swapped: r->n, 16B store)
__global__ __launch_bounds__(256) void gemm_bf16(const bf16* __restrict__ A,
                                                 const bf16* __restrict__ Bt,
                                                 void* __restrict__ Cout,
                                                 int M, int N, int K, int mode) {
    __shared__ bf16 As[2][128 * 32];
    __shared__ bf16 Bs[2][64 * 32];
    const int tid = threadIdx.x;
    const int wave = tid >> 6, lane = tid & 63;
    const int quad = lane >> 4, l16 = lane & 15;
    const int wr = wave >> 1, wc = wave & 1;
    const int m0 = blockIdx.y * 128, n0 = blockIdx.x * 64;
    const int z = blockIdx.z;
    const bf16* Bz = Bt + (size_t)z * N * K;
    const bool swapped = (mode == 1) || (z < 2);

    const int lrow = lane >> 2, lcol = (lane & 3) << 3;
    const bf16* ag = A  + (size_t)(m0 + wave * 32 + lrow) * K + lcol;
    const bf16* bg = Bz + (size_t)(n0 + wave * 16 + lrow) * K + lcol;
    const int a_off = (wave * 32 + lrow) * 32 + lcol;
    const int b_off = (wave * 16 + lrow) * 32 + lcol;

    f32x4 acc[4][2];
    for (int mi = 0; mi < 4; ++mi)
        for (int ni = 0; ni < 2; ++ni) acc[mi][ni] = (f32x4){0.f, 0.f, 0.f, 0.f};

    for (int kb = 0; kb < K; kb += 64) {
        GL2LDS16(ag + kb,                       &As[0][a_off]);
        GL2LDS16(ag + (size_t)16 * K + kb,      &As[0][a_off + 16 * 32]);
        GL2LDS16(ag + kb + 32,                  &As[1][a_off]);
        GL2LDS16(ag + (size_t)16 * K + kb + 32, &As[1][a_off + 16 * 32]);
        GL2LDS16(bg + kb,                       &Bs[0][b_off]);
        GL2LDS16(bg + kb + 32,                  &Bs[1][b_off]);
        __syncthreads();   // drains vmcnt -> LDS writes visible

        for (int half = 0; half < 2; ++half) {
            bf16x8 af[4], bfr[2];
            for (int mi = 0; mi < 4; ++mi)
                af[mi] = *(const bf16x8*)&As[half][(wr * 64 + mi * 16 + l16) * 32 + quad * 8];
            for (int ni = 0; ni < 2; ++ni)
                bfr[ni] = *(const bf16x8*)&Bs[half][(wc * 32 + ni * 16 + l16) * 32 + quad * 8];
            if (swapped) {
                for (int mi = 0; mi < 4; ++mi)
                    for (int ni = 0; ni < 2; ++ni)
                        acc[mi][ni] = __builtin_amdgcn_mfma_f32_16x16x32_bf16(
                            bfr[ni], af[mi], acc[mi][ni], 0, 0, 0);
            } else {
                for (int mi = 0; mi < 4; ++mi)
                    for (int ni = 0; ni < 2; ++ni)
                        acc[mi][ni] = __builtin_amdgcn_mfma_f32_16x16x32_bf16(
                            af[mi], bfr[ni], acc[mi][ni], 0, 0, 0);
            }
        }
        __syncthreads();
    }

    if (mode == 0) {
        bf16* Cb = (bf16*)Cout + (size_t)z * M * N;
        const float qscale = (z == 0) ? 0.180336887f : 1.0f;  // 0.125 * log2(e) folded into Q
        if (z < 2) {
            for (int mi = 0; mi < 4; ++mi)
                for (int ni = 0; ni < 2; ++ni) {
                    int m = m0 + wr * 64 + mi * 16 + l16;
                    int n = n0 + wc * 32 + ni * 16 + quad * 4;
                    int b = m >> 11, t = m & (T_ - 1);
                    int h = n >> 6, d = n & (HD - 1);
                    bf16 o4[4];
                    for (int r = 0; r < 4; ++r) o4[r] = (bf16)(acc[mi][ni][r] * qscale);
                    *(uint2*)&Cb[(((((size_t)b * H_ + h) * T_ + t) << 6) + d)] =
                        *(const uint2*)o4;
                }
        } else {
            for (int mi = 0; mi < 4; ++mi)
                for (int ni = 0; ni < 2; ++ni) {
                    int m = m0 + wr * 64 + mi * 16 + quad * 4;
                    int n = n0 + wc * 32 + ni * 16 + l16;
                    int b = m >> 11, t = m & (T_ - 1);
                    int h = n >> 6, d = n & (HD - 1);
                    bf16 o4[4];
                    for (int r = 0; r < 4; ++r) o4[r] = (bf16)acc[mi][ni][r];
                    *(uint2*)&Cb[((((size_t)b * H_ + h) * HD + d) * T_ + t)] =
                        *(const uint2*)o4;
                }
        }
    } else {
        float* Cf = (float*)Cout;
        for (int mi = 0; mi < 4; ++mi)
            for (int ni = 0; ni < 2; ++ni) {
                int m = m0 + wr * 64 + mi * 16 + l16;
                int n = n0 + wc * 32 + ni * 16 + quad * 4;
                *(f32x4*)&Cf[(size_t)m * N + n] = acc[mi][ni];
            }
    }
}

// ---------------------------------------------------------------- flash attention
// Br=128 (8 waves, 512 thr), Bc=128, S^T form. Q pre-scaled by 0.125*log2e in GEMM.
// __launch_bounds__(512, 4): VGPR cap 128 (R11's (512,8) capped at 64 -> total spill,
// 214 MB scratch writes). Items per bh (LPT): qt>=8 split at tile 8; qt<8 full.
__device__ __constant__ unsigned char ITEM_QT[24] = {
    8,9,10,11,12,13,14,15, 7,15, 6,14, 5,13, 4,12, 3,11, 2,10, 1,9, 0,8};
__device__ __constant__ unsigned char ITEM_KIND[24] = {  // 0=full 1=chunk0 2=chunk1
    1,1,1,1,1,1,1,1, 0,2, 0,2, 0,2, 0,2, 0,2, 0,2, 0,2, 0,2};

#define LDK 72
#define LDP 136

__global__ __launch_bounds__(512, 4) void attn_kernel(const bf16* __restrict__ Q,
                                                      const bf16* __restrict__ K,
                                                      const bf16* __restrict__ Vt,
                                                      bf16* __restrict__ O,
                                                      float* __restrict__ Opart,
                                                      float2* __restrict__ ML) {
    __shared__ bf16 Ks[128 * LDK];  // [key][dim]
    __shared__ bf16 Vs[64 * LDP];   // [dim][key]

    const int bh = blockIdx.x;                 // 0..31
    const int item = blockIdx.y;               // 0..23 (descending size)
    const int qt = ITEM_QT[item];              // 128-row q tile
    const int kind = ITEM_KIND[item];
    const int h = bh & (H_ - 1), b = bh >> 4;
    const int tid = threadIdx.x;
    const int wave = tid >> 6, lane = tid & 63;
    const int quad = lane >> 4, l16 = lane & 15;

    const bf16* Qb = Q + (size_t)bh * T_ * HD;
    const bf16* Kb = K + (size_t)bh * T_ * HD;
    const bf16* Vb = Vt + (size_t)bh * HD * T_;   // [hd][T]

    const float slope2 = exp2f(-0.5f * (float)(h + 1)) * 1.44269504f;  // log2-domain slope

    bf16x8 qf[2];
    {
        const bf16* qrow = Qb + (size_t)(qt * 128 + wave * 16 + l16) * HD + quad * 8;
        qf[0] = *(const bf16x8*)(qrow);
        qf[1] = *(const bf16x8*)(qrow + 32);
    }

    f32x4 acc[4];                    // O^T: d = df*16+quad*4+r, query = l16
    for (int df = 0; df < 4; ++df) acc[df] = (f32x4){0.f, 0.f, 0.f, 0.f};
    float m_run = -INFINITY, l_run = 0.f;

    const int qglob = qt * 128 + wave * 16 + l16;
    const int nkt = qt + 1;                        // 128-key tiles for full row
    const int kt0 = (kind == 2) ? 8 : 0;
    const int kt1 = (kind == 1) ? 8 : nkt;

    for (int kt = kt0; kt < kt1; ++kt) {
        const bool last = (kt == nkt - 1);         // chunk0 never reaches nkt-1
        __syncthreads();
        for (int it = 0; it < 2; ++it) {
            int idx = it * 512 + tid;              // 1024 slots
            int rk = idx >> 3, ck = (idx & 7) << 3;
            *(bf16x8*)&Ks[rk * LDK + ck] =
                *(const bf16x8*)(Kb + (size_t)(kt * 128 + rk) * HD + ck);
            int rv = idx >> 4, cv = (idx & 15) << 3;
            *(bf16x8*)&Vs[rv * LDP + cv] =
                *(const bf16x8*)(Vb + (size_t)rv * T_ + kt * 128 + cv);
        }
        __syncthreads();

        f32x4 s[8];
        for (int nf = 0; nf < 8; ++nf) {
            bf16x8 kf0 = *(const bf16x8*)&Ks[(nf * 16 + l16) * LDK + quad * 8];
            bf16x8 kf1 = *(const bf16x8*)&Ks[(nf * 16 + l16) * LDK + 32 + quad * 8];
            f32x4 zz = (f32x4){0.f, 0.f, 0.f, 0.f};
            zz = __builtin_amdgcn_mfma_f32_16x16x32_bf16(kf0, qf[0], zz, 0, 0, 0);
            zz = __builtin_amdgcn_mfma_f32_16x16x32_bf16(kf1, qf[1], zz, 0, 0, 0);
            s[nf] = zz;
        }

        // Q pre-scaled -> s already in log2 domain; add alibi, mask last tile
        const int jbase = kt * 128 + quad * 4;
        for (int nf = 0; nf < 8; ++nf)
            for (int r = 0; r < 4; ++r) {
                int j = jbase + nf * 16 + r;
                s[nf][r] = s[nf][r] + slope2 * (float)(j - (T_ - 1));
            }
        if (last) {
            for (int nf = 0; nf < 8; ++nf)
                for (int r = 0; r < 4; ++r)
                    if (jbase + nf * 16 + r > qglob) s[nf][r] = -INFINITY;
        }

        float mx = -INFINITY;
        for (int nf = 0; nf < 8; ++nf) {
            float a = fmaxf(fmaxf(s[nf][0], s[nf][1]), fmaxf(s[nf][2], s[nf][3]));
            mx = fmaxf(mx, a);
        }
        mx = fmaxf(mx, __shfl_xor(mx, 16, 64));
        mx = fmaxf(mx, __shfl_xor(mx, 32, 64));
        const float mnew = fmaxf(m_run, mx);
        const float alpha = exp2f(m_run - mnew);
        m_run = mnew;

        float rs = 0.f;
        bf16x4 pf[8];
        for (int nf = 0; nf < 8; ++nf) {
            float p0 = exp2f(s[nf][0] - mnew);
            float p1 = exp2f(s[nf][1] - mnew);
            float p2 = exp2f(s[nf][2] - mnew);
            float p3 = exp2f(s[nf][3] - mnew);
            rs += (p0 + p1) + (p2 + p3);
            pf[nf] = (bf16x4){(bf16)p0, (bf16)p1, (bf16)p2, (bf16)p3};
        }
        rs += __shfl_xor(rs, 16, 64);
        rs += __shfl_xor(rs, 32, 64);
        l_run = l_run * alpha + rs;
        for (int df = 0; df < 4; ++df) acc[df] *= alpha;

        for (int nf = 0; nf < 8; ++nf)
            for (int df = 0; df < 4; ++df) {
                bf16x4 vf = *(const bf16x4*)&Vs[(df * 16 + l16) * LDP + nf * 16 + quad * 4];
                acc[df] = mfma16x16x16(vf, pf[nf], acc[df]);
            }
    }

    if (kind == 0) {
        const float inv = 1.0f / l_run;
        for (int df = 0; df < 4; ++df) {
            bf16 o4[4];
            for (int r = 0; r < 4; ++r) o4[r] = (bf16)(acc[df][r] * inv);
            *(uint2*)&O[(((size_t)b * T_ + qglob) * H_ + h) * HD + df * 16 + quad * 4] =
                *(const uint2*)o4;
        }
    } else {
        const int pidx = (bh * 8 + (qt - 8)) * 2 + (kind == 2 ? 1 : 0);
        const int ql = wave * 16 + l16;        // 0..127
        float* dst = Opart + (size_t)pidx * 8192 + ql * 64;
        for (int df = 0; df < 4; ++df)
            *(f32x4*)&dst[df * 16 + quad * 4] = acc[df];
        if (quad == 0) ML[pidx * 128 + ql] = make_float2(m_run, l_run);
    }
}

// ---------------------------------------------------------------- partial merge
// grid (8, 32) x 512 thr: q = tid>>2 (0..127), d-chunk = (tid&3)*16.
__global__ __launch_bounds__(512) void attn_merge(const float* __restrict__ Opart,
                                                  const float2* __restrict__ ML,
                                                  bf16* __restrict__ O) {
    const int qt = 8 + blockIdx.x, bh = blockIdx.y;
    const int h = bh & (H_ - 1), b = bh >> 4;
    const int tid = threadIdx.x;
    const int q = tid >> 2, dc = (tid & 3) << 4;
    const int p0 = (bh * 8 + blockIdx.x) * 2, p1 = p0 + 1;

    const float2 ml0 = ML[p0 * 128 + q], ml1 = ML[p1 * 128 + q];
    const float M = fmaxf(ml0.x, ml1.x);
    const float e0 = exp2f(ml0.x - M), e1 = exp2f(ml1.x - M);
    const float inv = 1.0f / (e0 * ml0.y + e1 * ml1.y);

    const float* a = Opart + (size_t)p0 * 8192 + q * 64 + dc;
    const float* c = Opart + (size_t)p1 * 8192 + q * 64 + dc;
    bf16 o16[16];
    for (int j = 0; j < 4; ++j) {
        f32x4 va = *(const f32x4*)(a + j * 4);
        f32x4 vc = *(const f32x4*)(c + j * 4);
        for (int r = 0; r < 4; ++r)
            o16[j * 4 + r] = (bf16)((va[r] * e0 + vc[r] * e1) * inv);
    }
    const int t = qt * 128 + q;
    bf16* dst = O + (((size_t)b * T_ + t) * H_ + h) * HD + dc;
    *(bf16x8*)dst = *(const bf16x8*)o16;
    *(bf16x8*)(dst + 8) = *(const bf16x8*)(o16 + 8);
}

// ---------------------------------------------------------------- launch
extern "C" void kernel_launch(void* const* d_in, const int* in_sizes, int n_in,
                              void* d_out, int out_size, void* d_ws, size_t ws_size,
                              hipStream_t stream) {
    const float* x  = (const float*)d_in[0];
    const float* Wq = (const float*)d_in[1];
    const float* Wk = (const float*)d_in[2];
    const float* Wv = (const float*)d_in[3];
    const float* Wo = (const float*)d_in[4];
    float* out = (float*)d_out;

    const size_t M = (size_t)B_ * T_;        // 4096
    const size_t XE = M * D_;                // 4 Mi elems
    const size_t WE = (size_t)D_ * D_;       // 1 Mi elems

    char* ws = (char*)d_ws;
    size_t off = 0;
    auto carve = [&](size_t bytes) {
        void* p = ws + off;
        off += (bytes + 255) & ~(size_t)255;
        return p;
    };
    bf16* xb  = (bf16*)carve(XE * 2);        // x bf16; reused as attn_out later
    bf16* Wt  = (bf16*)carve(4 * WE * 2);    // Wq,Wk,Wv,Wo transposed [N][K]
    bf16* QKV = (bf16*)carve(3 * XE * 2);    // Q,K [B,H,T,hd]; V [B,H,hd,T]
    float*  Opart = (float*)carve(32 * 8 * 2 * 8192 * sizeof(float));    // 16.8 MB
    float2* MLbuf = (float2*)carve(32 * 8 * 2 * 128 * sizeof(float2));   // 0.5 MB
    bf16* attn = xb;  // safe: xb fully consumed by QKV gemm before attn_kernel runs

    prep_inputs<<<dim3(16, 16, 20), 256, 0, stream>>>(x, Wq, Wk, Wv, Wo, xb, Wt);

    gemm_bf16<<<dim3(D_ / 64, M / 128, 3), 256, 0, stream>>>(xb, Wt, QKV,
                                                             (int)M, D_, D_, 0);
    attn_kernel<<<dim3(32, 24), 512, 0, stream>>>(QKV, QKV + XE, QKV + 2 * XE,
                                                  attn, Opart, MLbuf);
    attn_merge<<<dim3(8, 32), 512, 0, stream>>>(Opart, MLbuf, attn);
    gemm_bf16<<<dim3(D_ / 64, M / 128, 1), 256, 0, stream>>>(attn, Wt + 3 * WE, out,
                                                             (int)M, D_, D_, 1);
}